// Round 4
// baseline (576.033 us; speedup 1.0000x reference)
//
#include <hip/hip_runtime.h>

#define NC 32
#define NR 512
#define BLK 512
#define PPB 512               // points per block
#define PTS_PER_IT (BLK / 8)  // 64 points per unrolled iter (8 threads/point)
#define ITERS (PPB / PTS_PER_IT)  // 8
#define RS 36                 // words per row: 32 comps + 4 pad (144 B)
#define AXW (NR * RS)         // 18432 words per axis image
#define LDS_BYTES (AXW * 4)   // 73728 B -> 2 blocks/CU (147456 <= 163840)

// ---------------------------------------------------------------------------
// Kernel 1: build padded axis images in ws. Image a is the exact byte image
// the encode kernel wants in LDS: [row 0..511][comp 0..31, pad x4], row
// stride 36 words (144 B). Pads are never read (j4 <= 28 -> words <= 35f+31).
// ws is re-poisoned by the harness every iteration (verified unconditional in
// R3), so this must run every launch -- it's ~3 us.
// ---------------------------------------------------------------------------
__global__ __launch_bounds__(256) void make_images(
    const float* __restrict__ vx, const float* __restrict__ vy,
    const float* __restrict__ vz, float* __restrict__ ws) {
  int u = blockIdx.x * 256 + threadIdx.x;           // 0 .. 3*16384-1
  if (u >= 3 * NC * NR) return;
  int table = u >> 14;
  int e = u & (NC * NR - 1);                        // c*512 + r
  int c = e >> 9;
  int r = e & (NR - 1);
  const float* src = (table == 0) ? vx : (table == 1) ? vy : vz;
  ws[table * AXW + r * RS + c] = src[e];
}

// ---------------------------------------------------------------------------
// Kernel 2: axis-phased encode. One 512-thread block owns 512 points.
// Per axis a in {x,y,z}:
//   barrier; stage image a (9x global_load_lds_dwordx4/thread, linear LDS,
//   no VALU repack); barrier; lerp all 512 points, acc *= result.
// Then one coalesced float4 store pass (full 128-B line per point from 8
// adjacent threads).
// LDS reads are bank-conflict-free by construction: one point's 8 lanes read
// 32 consecutive words (all 32 banks once); 8 points/wave-instr = balanced
// 8-deep = the ds_read_b128 throughput floor, independent of the random row.
// 72 KiB LDS + <=128 VGPR -> 2 blocks/CU, so staging/barriers of one block
// overlap compute of the other (this was the R2/R3 serialization).
// ---------------------------------------------------------------------------
__global__ __launch_bounds__(BLK, 4) void cp_encode(
    const float* __restrict__ pos, const float* __restrict__ ws,
    float* __restrict__ out, int npts) {
  extern __shared__ float lds[];
  const int tid = threadIdx.x;
  const int base_p = blockIdx.x * PPB;
  const int j4 = (tid & 7) << 2;                    // comp quad 0,4,..,28
  const int pofs = tid >> 3;                        // 0..63

  // Load each owned point's coords once (L1-broadcast across the 8 sharers).
  float px[ITERS], py[ITERS], pz[ITERS];
#pragma unroll
  for (int it = 0; it < ITERS; ++it) {
    int p = base_p + pofs + it * PTS_PER_IT;
    int pc = min(p, npts - 1);
    px[it] = pos[3 * pc + 0];
    py[it] = pos[3 * pc + 1];
    pz[it] = pos[3 * pc + 2];
  }

  float4 acc[ITERS];

#pragma unroll
  for (int a = 0; a < 3; ++a) {
    __syncthreads();                                // prev-axis readers done
    const float* g = ws + a * AXW;
#pragma unroll
    for (int k = 0; k < 9; ++k) {                   // 9*512*16 B = 73728 B
      int o = (k * BLK + tid) << 2;                 // float index
      __builtin_amdgcn_global_load_lds(
          (const __attribute__((address_space(1))) unsigned int*)(g + o),
          (__attribute__((address_space(3))) unsigned int*)(lds + o),
          16, 0, 0);
    }
    __syncthreads();                                // drains vmcnt, publishes

#pragma unroll
    for (int it = 0; it < ITERS; ++it) {
      float x = (a == 0) ? px[it] : (a == 1) ? py[it] : pz[it];
      // grid_sample(align_corners=True); x in [-1,1] so zero-pad is dead.
      // f clamped to 510 so row f+1 is valid; at ix==511, w==1 -> row 511.
      float ix = fmaf(x, 255.5f, 255.5f);
      ix = fminf(fmaxf(ix, 0.0f), 511.0f);
      float f = fminf(floorf(ix), 510.0f);
      float w = ix - f;
      const float* adr = lds + (int)f * RS + j4;
      float4 v0 = *(const float4*)adr;              // ds_read_b128
      float4 v1 = *(const float4*)(adr + RS);       // row f+1 = +144 B
      float4 s;
      s.x = fmaf(w, v1.x - v0.x, v0.x);
      s.y = fmaf(w, v1.y - v0.y, v0.y);
      s.z = fmaf(w, v1.z - v0.z, v0.z);
      s.w = fmaf(w, v1.w - v0.w, v0.w);
      if (a == 0) {
        acc[it] = s;
      } else {
        acc[it].x *= s.x;
        acc[it].y *= s.y;
        acc[it].z *= s.z;
        acc[it].w *= s.w;
      }
    }
  }

#pragma unroll
  for (int it = 0; it < ITERS; ++it) {
    int p = base_p + pofs + it * PTS_PER_IT;
    if (p < npts)
      *(float4*)(out + (size_t)p * NC + j4) = acc[it];  // coalesced 128-B/pt
  }
}

// ---------------------------------------------------------------------------
// Fallback if ws can't hold the images: direct scattered-read path.
// ---------------------------------------------------------------------------
__device__ __forceinline__ float4 sample4_u(const float* __restrict__ t,
                                            float x, int c4) {
  float ix = (x + 1.0f) * 0.5f * (float)(NR - 1);
  float f = floorf(ix);
  float w = ix - f;
  int i0 = (int)f;
  int i1 = i0 + 1;
  float m0 = (i0 >= 0 && i0 < NR) ? (1.0f - w) : 0.0f;
  float m1 = (i1 >= 0 && i1 < NR) ? w : 0.0f;
  int ci0 = min(max(i0, 0), NR - 1);
  int ci1 = min(max(i1, 0), NR - 1);
  float4 r;
  float* rp = (float*)&r;
  for (int j = 0; j < 4; ++j) {
    float v0 = t[(c4 + j) * NR + ci0];
    float v1 = t[(c4 + j) * NR + ci1];
    rp[j] = v0 * m0 + v1 * m1;
  }
  return r;
}

__global__ __launch_bounds__(256) void cp_encode_global(
    const float* __restrict__ pos, const float* __restrict__ vx,
    const float* __restrict__ vy, const float* __restrict__ vz,
    float* __restrict__ out, int npts) {
  int t = blockIdx.x * 256 + threadIdx.x;
  int p = t >> 3;
  if (p >= npts) return;
  int c4 = (t & 7) * 4;
  float x = pos[3 * p + 0];
  float y = pos[3 * p + 1];
  float z = pos[3 * p + 2];
  float4 fx = sample4_u(vx, x, c4);
  float4 fy = sample4_u(vy, y, c4);
  float4 fz = sample4_u(vz, z, c4);
  float4 r;
  r.x = fx.x * fy.x * fz.x;
  r.y = fx.y * fy.y * fz.y;
  r.z = fx.z * fy.z * fz.z;
  r.w = fx.w * fy.w * fz.w;
  *(float4*)(out + (long long)p * NC + c4) = r;
}

extern "C" void kernel_launch(void* const* d_in, const int* in_sizes, int n_in,
                              void* d_out, int out_size, void* d_ws,
                              size_t ws_size, hipStream_t stream) {
  const float* pos = (const float*)d_in[0];
  const float* vx = (const float*)d_in[1];
  const float* vy = (const float*)d_in[2];
  const float* vz = (const float*)d_in[3];
  float* out = (float*)d_out;
  int npts = in_sizes[0] / 3;
  if (npts <= 0) return;

  const size_t ibytes = (size_t)3 * AXW * sizeof(float);  // 216 KiB

  if (ws_size >= ibytes) {
    static int lds_attr_set = 0;
    if (!lds_attr_set) {
      hipFuncSetAttribute((const void*)cp_encode,
                          hipFuncAttributeMaxDynamicSharedMemorySize,
                          LDS_BYTES);
      lds_attr_set = 1;
    }
    float* ws = (float*)d_ws;
    int tb = (3 * NC * NR + 255) / 256;
    make_images<<<tb, 256, 0, stream>>>(vx, vy, vz, ws);
    int blocks = (npts + PPB - 1) / PPB;
    cp_encode<<<blocks, BLK, LDS_BYTES, stream>>>(pos, ws, out, npts);
  } else {
    int blocks = (npts * 8 + 255) / 256;
    cp_encode_global<<<blocks, 256, 0, stream>>>(pos, vx, vy, vz, out, npts);
  }
}

// Round 6
// 414.853 us; speedup vs baseline: 1.3885x; 1.3885x over previous
//
#include <hip/hip_runtime.h>

#define NC 32
#define NR 512
#define BLK 512
#define NGRP 192              // disjoint point-range groups
#define NCLS 4                // component classes (8 comps each)
#define GRID (NGRP * NCLS)    // 768 blocks = 3/CU * 256 CU (all co-resident)
#define CW 24                 // words per LDS row: 3 axes * 8 comps (96 B)
#define CLW (NR * CW)         // 12288 words = 48 KiB per class image

// ---------------------------------------------------------------------------
// Kernel 1: build 4 class images in ws. Class q holds comps q*8..q*8+7 of all
// three axes, laid out exactly as the encode kernel's LDS wants it:
//   ws[q*CLW + r*24 + a*8 + (c&7)] = v_a[c][r]
// Row stride 24 words: (24*r) mod 32 cycles {0,24,16,8}, so each point's
// 8-word read window maps to one 8-bank group; reads rotate over 4 groups.
// ---------------------------------------------------------------------------
__global__ __launch_bounds__(256) void make_images(
    const float* __restrict__ vx, const float* __restrict__ vy,
    const float* __restrict__ vz, float* __restrict__ ws) {
  int u = blockIdx.x * 256 + threadIdx.x;           // 0 .. 3*16384-1
  if (u >= 3 * NC * NR) return;
  int a = u >> 14;                                  // axis/table
  int e = u & (NC * NR - 1);                        // c*512 + r
  int c = e >> 9;
  int r = e & (NR - 1);
  const float* src = (a == 0) ? vx : (a == 1) ? vy : vz;
  ws[(c >> 3) * CLW + r * CW + a * 8 + (c & 7)] = src[e];
}

// grid_sample(align_corners=True); x in [-1,1] so zero-pad is dead. f clamped
// to 510 so row f+1 is always in-image (at ix==511, w==1 -> full weight on
// row 511 -- exact reference match).
__device__ __forceinline__ float4 lerp4c(const float* __restrict__ lds,
                                         float x, int base) {
  float ix = fmaf(x, 255.5f, 255.5f);
  ix = fminf(fmaxf(ix, 0.0f), 511.0f);
  float f = fminf(floorf(ix), 510.0f);
  float w = ix - f;
  const float* adr = lds + (int)f * CW + base;
  float4 v0 = *(const float4*)adr;                  // ds_read_b128
  float4 v1 = *(const float4*)(adr + CW);           // row f+1 = +96 B
  float4 r;
  r.x = fmaf(w, v1.x - v0.x, v0.x);
  r.y = fmaf(w, v1.y - v0.y, v0.y);
  r.z = fmaf(w, v1.z - v0.z, v0.z);
  r.w = fmaf(w, v1.w - v0.w, v0.w);
  return r;
}

// ---------------------------------------------------------------------------
// Kernel 2: persistent class-blocks. Block (grp, cls) stages its 48-KiB class
// image into static LDS ONCE (6x global_load_lds_dwordx4 per thread), then
// iterates points [grp*chunk, (grp+1)*chunk) computing comps cls*8..+7.
// Staging total = 768 * 48 KiB = 36 MB (vs R4's 844 MB). No per-thread
// arrays -> no spills. 2 threads/point (float4 quad each).
// bid->(grp,cls) mapping puts the 4 class-blocks of a group on the SAME XCD
// (bid%8 round-robin) within 32 bids, so pos reads L2-share and the four
// 32-B out sectors of each 128-B line merge in that XCD's L2.
// Co-residency is performance-only: no inter-block communication exists.
// ---------------------------------------------------------------------------
__global__ __launch_bounds__(BLK, 6) void cp_encode(
    const float* __restrict__ pos, const float* __restrict__ ws,
    float* __restrict__ out, int npts, int chunk) {
  __shared__ float lds[CLW];
  const int tid = threadIdx.x;
  const int bid = blockIdx.x;
  const int xcd = bid & 7;
  const int j = bid >> 3;                           // 0..95 within xcd
  const int cls = j & 3;
  const int grp = xcd * (NGRP / 8) + (j >> 2);

  // Stage class image once: 3072 float4 = 6 per thread, linear LDS dest.
  const float* g = ws + cls * CLW;
#pragma unroll
  for (int k = 0; k < 6; ++k) {
    int o = (k * BLK + tid) << 2;                   // float index
    __builtin_amdgcn_global_load_lds(
        (const __attribute__((address_space(1))) unsigned int*)(g + o),
        (__attribute__((address_space(3))) unsigned int*)(lds + o),
        16, 0, 0);
  }
  __syncthreads();                                  // drains vmcnt, publishes

  const int c0 = (tid & 1) << 2;                    // comp quad within class
  const int oco = cls * 8 + c0;                     // out comp offset
  const int gbase = grp * chunk;
  const int pend = min(gbase + chunk, npts);

  for (int p = gbase + (tid >> 1); p < pend; p += (BLK / 2)) {
    float x = pos[3 * p + 0];
    float y = pos[3 * p + 1];
    float z = pos[3 * p + 2];
    float4 fx = lerp4c(lds, x, c0);                 // axis 0 at base 0
    float4 fy = lerp4c(lds, y, 8 + c0);             // axis 1 at base 8
    float4 fz = lerp4c(lds, z, 16 + c0);            // axis 2 at base 16
    float4 r;
    r.x = fx.x * fy.x * fz.x;
    r.y = fx.y * fy.y * fz.y;
    r.z = fx.z * fy.z * fz.z;
    r.w = fx.w * fy.w * fz.w;
    *(float4*)(out + (size_t)p * NC + oco) = r;     // 32-B sector per point
  }
}

// ---------------------------------------------------------------------------
// Fallback if ws is too small: direct scattered-read path.
// ---------------------------------------------------------------------------
__device__ __forceinline__ float4 sample4_u(const float* __restrict__ t,
                                            float x, int c4) {
  float ix = (x + 1.0f) * 0.5f * (float)(NR - 1);
  float f = floorf(ix);
  float w = ix - f;
  int i0 = (int)f;
  int i1 = i0 + 1;
  float m0 = (i0 >= 0 && i0 < NR) ? (1.0f - w) : 0.0f;
  float m1 = (i1 >= 0 && i1 < NR) ? w : 0.0f;
  int ci0 = min(max(i0, 0), NR - 1);
  int ci1 = min(max(i1, 0), NR - 1);
  float4 r;
  float* rp = (float*)&r;
  for (int j = 0; j < 4; ++j) {
    float v0 = t[(c4 + j) * NR + ci0];
    float v1 = t[(c4 + j) * NR + ci1];
    rp[j] = v0 * m0 + v1 * m1;
  }
  return r;
}

__global__ __launch_bounds__(256) void cp_encode_global(
    const float* __restrict__ pos, const float* __restrict__ vx,
    const float* __restrict__ vy, const float* __restrict__ vz,
    float* __restrict__ out, int npts) {
  int t = blockIdx.x * 256 + threadIdx.x;
  int p = t >> 3;
  if (p >= npts) return;
  int c4 = (t & 7) * 4;
  float x = pos[3 * p + 0];
  float y = pos[3 * p + 1];
  float z = pos[3 * p + 2];
  float4 fx = sample4_u(vx, x, c4);
  float4 fy = sample4_u(vy, y, c4);
  float4 fz = sample4_u(vz, z, c4);
  float4 r;
  r.x = fx.x * fy.x * fz.x;
  r.y = fx.y * fy.y * fz.y;
  r.z = fx.z * fy.z * fz.z;
  r.w = fx.w * fy.w * fz.w;
  *(float4*)(out + (long long)p * NC + c4) = r;
}

extern "C" void kernel_launch(void* const* d_in, const int* in_sizes, int n_in,
                              void* d_out, int out_size, void* d_ws,
                              size_t ws_size, hipStream_t stream) {
  const float* pos = (const float*)d_in[0];
  const float* vx = (const float*)d_in[1];
  const float* vy = (const float*)d_in[2];
  const float* vz = (const float*)d_in[3];
  float* out = (float*)d_out;
  int npts = in_sizes[0] / 3;
  if (npts <= 0) return;

  const size_t ibytes = (size_t)NCLS * CLW * sizeof(float);  // 192 KiB

  if (ws_size >= ibytes) {
    float* ws = (float*)d_ws;
    int tb = (3 * NC * NR + 255) / 256;
    make_images<<<tb, 256, 0, stream>>>(vx, vy, vz, ws);
    int chunk = (npts + NGRP - 1) / NGRP;
    if (chunk < 1) chunk = 1;
    cp_encode<<<GRID, BLK, 0, stream>>>(pos, ws, out, npts, chunk);
  } else {
    int blocks = (npts * 8 + 255) / 256;
    cp_encode_global<<<blocks, 256, 0, stream>>>(pos, vx, vy, vz, out, npts);
  }
}